// Round 1
// baseline (1656.005 us; speedup 1.0000x reference)
//
#include <hip/hip_runtime.h>
#include <cmath>

namespace {
constexpr int BPTS  = 16384;
constexpr int NPOSE = 32;
constexpr int KV    = 8;
constexpr int HD    = 256;
constexpr int TM    = 64;

constexpr size_t OFF_XLOCAL = 0;
constexpr size_t OFF_XLA    = (size_t)BPTS * 3;                      // x_local_all [32,16384,3]
constexpr size_t OFF_MINENC = OFF_XLA + (size_t)NPOSE * BPTS * 3;    // min_encodings [16384,32]
constexpr size_t OFF_POSEQ  = OFF_MINENC + (size_t)BPTS * NPOSE;     // inv_pose_q [16384,4,4]
constexpr size_t OFF_CLASS  = OFF_POSEQ + (size_t)BPTS * 16;         // pred_class [16384,1]
constexpr size_t OFF_PRED   = OFF_CLASS + (size_t)BPTS;              // pred_prob.T [16384,32]
constexpr size_t OFF_VECQ   = OFF_PRED + (size_t)BPTS * NPOSE;       // vec_q [16384,8]
}

// One GEMM layer: acc[8][8] = bias; acc += inT^T @ W  (64 rows x 256 cols per block)
#define GEMM_LAYER(Wp, Bp, KDIM, INBUF)                                          \
    {                                                                            \
        const float4* bp = (const float4*)((Bp) + tc*8);                         \
        float4 bA = bp[0], bB = bp[1];                                           \
        _Pragma("unroll")                                                        \
        for (int i = 0; i < 8; ++i) {                                            \
            acc[i][0]=bA.x; acc[i][1]=bA.y; acc[i][2]=bA.z; acc[i][3]=bA.w;      \
            acc[i][4]=bB.x; acc[i][5]=bB.y; acc[i][6]=bB.z; acc[i][7]=bB.w;      \
        }                                                                        \
        _Pragma("unroll 4")                                                      \
        for (int k = 0; k < (KDIM); ++k) {                                       \
            float4 a0 = *(const float4*)&INBUF[k][tr*8];                         \
            float4 a1 = *(const float4*)&INBUF[k][tr*8+4];                       \
            const float4* wp = (const float4*)((Wp) + k*HD + tc*8);              \
            float4 wv0 = wp[0], wv1 = wp[1];                                     \
            float a[8] = {a0.x,a0.y,a0.z,a0.w,a1.x,a1.y,a1.z,a1.w};              \
            float w[8] = {wv0.x,wv0.y,wv0.z,wv0.w,wv1.x,wv1.y,wv1.z,wv1.w};      \
            _Pragma("unroll")                                                    \
            for (int i = 0; i < 8; ++i)                                          \
                _Pragma("unroll")                                                \
                for (int j = 0; j < 8; ++j)                                      \
                    acc[i][j] = fmaf(a[i], w[j], acc[i][j]);                     \
        }                                                                        \
    }

// relu(acc) -> hbufT (transposed: hbufT[col][row])
#define STORE_H()                                                                \
    _Pragma("unroll")                                                            \
    for (int j = 0; j < 8; ++j) {                                                \
        const int c = tc*8 + j;                                                  \
        float4 v0 = make_float4(fmaxf(acc[0][j],0.f), fmaxf(acc[1][j],0.f),      \
                                fmaxf(acc[2][j],0.f), fmaxf(acc[3][j],0.f));     \
        float4 v1 = make_float4(fmaxf(acc[4][j],0.f), fmaxf(acc[5][j],0.f),      \
                                fmaxf(acc[6][j],0.f), fmaxf(acc[7][j],0.f));     \
        *(float4*)&hbufT[c][tr*8]   = v0;                                        \
        *(float4*)&hbufT[c][tr*8+4] = v1;                                        \
    }

__global__ __launch_bounds__(256, 2)
void mlp_kernel(const float* __restrict__ x_world,
                const float* __restrict__ inv_poses,
                const float* __restrict__ w0, const float* __restrict__ b0,
                const float* __restrict__ w1, const float* __restrict__ b1,
                const float* __restrict__ w2, const float* __restrict__ b2,
                const float* __restrict__ w3, const float* __restrict__ b3,
                float* __restrict__ out)
{
    __shared__ float featT[40][TM];   // embedded features, transposed
    __shared__ float hbufT[HD][TM];   // activations, transposed (reused in place)
    __shared__ float w3s[HD];
    __shared__ float predp[4][TM];

    const int tid = threadIdx.x;
    const int bid = blockIdx.x;
    const int n_idx = bid >> 8;          // 256 blocks per pose (16384/64)
    const int bbase = (bid & 255) * TM;

    w3s[tid] = w3[tid];

    // ---- pose transform + positional encoding (all 4 waves share the 64 points) ----
    {
        const int r = tid & 63;
        const int q = tid >> 6;          // 0..3
        const int b = bbase + r;
        const float xw0 = x_world[b*3+0];
        const float xw1 = x_world[b*3+1];
        const float xw2 = x_world[b*3+2];
        const float* P = inv_poses + n_idx*16;
        float xl[3];
        #pragma unroll
        for (int x = 0; x < 3; ++x)
            xl[x] = P[x*4+3] + P[x*4+0]*xw0 + P[x*4+1]*xw1 + P[x*4+2]*xw2;
        if (q == 0) {
            float* xla = out + OFF_XLA + ((size_t)n_idx*BPTS + b)*3;
            #pragma unroll
            for (int x = 0; x < 3; ++x) { xla[x] = xl[x]; featT[x][r] = xl[x]; }
        }
        // 12 jobs (6 octaves x sin/cos), 3 per replica q
        #pragma unroll
        for (int t = 0; t < 3; ++t) {
            const int jj  = q*3 + t;
            const int oct = jj >> 1;
            const int fn  = jj & 1;
            const float s = (float)(1 << oct);
            #pragma unroll
            for (int x = 0; x < 3; ++x) {
                float a = xl[x] * s;
                featT[3 + 6*oct + 3*fn + x][r] = fn ? cosf(a) : sinf(a);
            }
        }
    }
    __syncthreads();

    const int tc = tid & 31;   // col group: cols tc*8 .. tc*8+7
    const int tr = tid >> 5;   // row group: rows tr*8 .. tr*8+7
    float acc[8][8];

    // ---- layer 0: feat(39) -> h0 ----
    GEMM_LAYER(w0, b0, 39, featT)
    STORE_H()                      // writes hbufT (distinct from featT) — no sync needed before
    __syncthreads();

    // ---- layer 1 ----
    GEMM_LAYER(w1, b1, HD, hbufT)
    __syncthreads();               // all reads of h0 done
    STORE_H()
    __syncthreads();

    // ---- layer 2 ----
    GEMM_LAYER(w2, b2, HD, hbufT)
    __syncthreads();
    STORE_H()
    __syncthreads();

    // ---- layer 3: pred[r] = sum_c h2[r][c]*w3[c] + b3 ----
    {
        const int r = tid & 63;
        const int q = tid >> 6;
        float s = 0.f;
        #pragma unroll 8
        for (int cc = 0; cc < 64; ++cc) {
            const int c = q*64 + cc;
            s = fmaf(hbufT[c][r], w3s[c], s);
        }
        predp[q][r] = s;
    }
    __syncthreads();
    if (tid < TM) {
        float p = predp[0][tid] + predp[1][tid] + predp[2][tid] + predp[3][tid] + b3[0];
        out[OFF_PRED + (size_t)(bbase + tid)*NPOSE + n_idx] = p;
    }
}

__global__ __launch_bounds__(256)
void select_kernel(const float* __restrict__ x_world,
                   const float* __restrict__ inv_poses,
                   const float* __restrict__ vector,
                   float* __restrict__ out)
{
    const int b = blockIdx.x * 256 + threadIdx.x;
    if (b >= BPTS) return;

    const float* pr = out + OFF_PRED + (size_t)b * NPOSE;
    float best = pr[0];
    int idx = 0;
    #pragma unroll
    for (int n = 1; n < NPOSE; ++n) {           // first-occurrence min == jnp.argmin
        float v = pr[n];
        if (v < best) { best = v; idx = n; }
    }

    float* me = out + OFF_MINENC + (size_t)b * NPOSE;
    #pragma unroll
    for (int n = 0; n < NPOSE; ++n) me[n] = (n == idx) ? 1.f : 0.f;

    const float* P = inv_poses + idx * 16;
    float* pq = out + OFF_POSEQ + (size_t)b * 16;
    #pragma unroll
    for (int m = 0; m < 16; ++m) pq[m] = P[m];

    const float xw0 = x_world[b*3+0], xw1 = x_world[b*3+1], xw2 = x_world[b*3+2];
    float* xl = out + OFF_XLOCAL + (size_t)b * 3;
    #pragma unroll
    for (int x = 0; x < 3; ++x)
        xl[x] = P[x*4+3] + P[x*4+0]*xw0 + P[x*4+1]*xw1 + P[x*4+2]*xw2;

    out[OFF_CLASS + b] = (float)idx;

    const float* vq = vector + idx * KV;
    float* ov = out + OFF_VECQ + (size_t)b * KV;
    #pragma unroll
    for (int m = 0; m < KV; ++m) ov[m] = vq[m];
}

extern "C" void kernel_launch(void* const* d_in, const int* in_sizes, int n_in,
                              void* d_out, int out_size, void* d_ws, size_t ws_size,
                              hipStream_t stream)
{
    const float* x_world   = (const float*)d_in[0];
    const float* inv_poses = (const float*)d_in[1];
    const float* vector    = (const float*)d_in[2];
    const float* w0 = (const float*)d_in[3];
    const float* b0 = (const float*)d_in[4];
    const float* w1 = (const float*)d_in[5];
    const float* b1 = (const float*)d_in[6];
    const float* w2 = (const float*)d_in[7];
    const float* b2 = (const float*)d_in[8];
    const float* w3 = (const float*)d_in[9];
    const float* b3 = (const float*)d_in[10];
    float* out = (float*)d_out;

    mlp_kernel<<<dim3(NPOSE * BPTS / TM), dim3(256), 0, stream>>>(
        x_world, inv_poses, w0, b0, w1, b1, w2, b2, w3, b3, out);
    select_kernel<<<dim3(BPTS / 256), dim3(256), 0, stream>>>(
        x_world, inv_poses, vector, out);
}

// Round 2
// 1579.202 us; speedup vs baseline: 1.0486x; 1.0486x over previous
//
#include <hip/hip_runtime.h>
#include <cmath>

namespace {
constexpr int BPTS  = 16384;
constexpr int NPOSE = 32;
constexpr int KV    = 8;
constexpr int HD    = 256;
constexpr int TM    = 64;
constexpr int FROW  = 44;     // feat row stride (pad 39->44, 16B-aligned, spreads banks)

constexpr size_t OFF_XLOCAL = 0;
constexpr size_t OFF_XLA    = (size_t)BPTS * 3;                      // x_local_all [32,16384,3]
constexpr size_t OFF_MINENC = OFF_XLA + (size_t)NPOSE * BPTS * 3;    // min_encodings [16384,32]
constexpr size_t OFF_POSEQ  = OFF_MINENC + (size_t)BPTS * NPOSE;     // inv_pose_q [16384,4,4]
constexpr size_t OFF_CLASS  = OFF_POSEQ + (size_t)BPTS * 16;         // pred_class [16384,1]
constexpr size_t OFF_PRED   = OFF_CLASS + (size_t)BPTS;              // pred_prob.T [16384,32]
constexpr size_t OFF_VECQ   = OFF_PRED + (size_t)BPTS * NPOSE;       // vec_q [16384,8]
}

// acc[i][j]: rows tr*8+i (64 rows), cols j<4 -> tc*4+j ; j>=4 -> 128+tc*4+(j-4)
// A-reads: float4 along k, same address across the 32-lane tc group -> LDS broadcast.
// Stores/weight-loads: half-wave contiguous 512B -> conflict-free / coalesced.
template<int KDIM, int RS>
__device__ __forceinline__ void gemm_layer(const float* __restrict__ W,
                                           const float* __restrict__ B,
                                           const float (*in)[RS],
                                           float acc[8][8], int tc, int tr)
{
    {
        float4 bA = *(const float4*)(B + tc*4);
        float4 bB = *(const float4*)(B + 128 + tc*4);
        #pragma unroll
        for (int i = 0; i < 8; ++i) {
            acc[i][0]=bA.x; acc[i][1]=bA.y; acc[i][2]=bA.z; acc[i][3]=bA.w;
            acc[i][4]=bB.x; acc[i][5]=bB.y; acc[i][6]=bB.z; acc[i][7]=bB.w;
        }
    }
    constexpr int K4 = KDIM & ~3;
    #pragma unroll 2
    for (int k = 0; k < K4; k += 4) {
        float4 a4[8];
        #pragma unroll
        for (int i = 0; i < 8; ++i) a4[i] = *(const float4*)&in[tr*8+i][k];
        #pragma unroll
        for (int kk = 0; kk < 4; ++kk) {
            float4 wA = *(const float4*)(W + (size_t)(k+kk)*HD + tc*4);
            float4 wB = *(const float4*)(W + (size_t)(k+kk)*HD + 128 + tc*4);
            #pragma unroll
            for (int i = 0; i < 8; ++i) {
                const float a = (kk==0) ? a4[i].x : (kk==1) ? a4[i].y
                              : (kk==2) ? a4[i].z : a4[i].w;
                acc[i][0] = fmaf(a, wA.x, acc[i][0]);
                acc[i][1] = fmaf(a, wA.y, acc[i][1]);
                acc[i][2] = fmaf(a, wA.z, acc[i][2]);
                acc[i][3] = fmaf(a, wA.w, acc[i][3]);
                acc[i][4] = fmaf(a, wB.x, acc[i][4]);
                acc[i][5] = fmaf(a, wB.y, acc[i][5]);
                acc[i][6] = fmaf(a, wB.z, acc[i][6]);
                acc[i][7] = fmaf(a, wB.w, acc[i][7]);
            }
        }
    }
    if constexpr (K4 < KDIM) {
        #pragma unroll
        for (int k = K4; k < KDIM; ++k) {
            float4 wA = *(const float4*)(W + (size_t)k*HD + tc*4);
            float4 wB = *(const float4*)(W + (size_t)k*HD + 128 + tc*4);
            #pragma unroll
            for (int i = 0; i < 8; ++i) {
                const float a = in[tr*8+i][k];
                acc[i][0] = fmaf(a, wA.x, acc[i][0]);
                acc[i][1] = fmaf(a, wA.y, acc[i][1]);
                acc[i][2] = fmaf(a, wA.z, acc[i][2]);
                acc[i][3] = fmaf(a, wA.w, acc[i][3]);
                acc[i][4] = fmaf(a, wB.x, acc[i][4]);
                acc[i][5] = fmaf(a, wB.y, acc[i][5]);
                acc[i][6] = fmaf(a, wB.z, acc[i][6]);
                acc[i][7] = fmaf(a, wB.w, acc[i][7]);
            }
        }
    }
}

__global__ __launch_bounds__(256, 2)
void mlp_kernel(const float* __restrict__ x_world,
                const float* __restrict__ inv_poses,
                const float* __restrict__ w0, const float* __restrict__ b0,
                const float* __restrict__ w1, const float* __restrict__ b1,
                const float* __restrict__ w2, const float* __restrict__ b2,
                const float* __restrict__ w3, const float* __restrict__ b3,
                float* __restrict__ out)
{
    __shared__ float feat[TM][FROW];   // embedded features, row-major
    __shared__ float h[TM][HD];        // activations, row-major (reused in place)
    __shared__ float predp[TM];

    const int tid = threadIdx.x;
    const int bid = blockIdx.x;
    const int n_idx = bid >> 8;          // 256 blocks per pose (16384/64)
    const int bbase = (bid & 255) * TM;

    // ---- pose transform + positional encoding (4 wave-replicas share 64 points) ----
    {
        const int r = tid & 63;
        const int q = tid >> 6;          // 0..3
        const int b = bbase + r;
        const float xw0 = x_world[b*3+0];
        const float xw1 = x_world[b*3+1];
        const float xw2 = x_world[b*3+2];
        const float* P = inv_poses + n_idx*16;
        float xl[3];
        #pragma unroll
        for (int x = 0; x < 3; ++x)
            xl[x] = P[x*4+3] + P[x*4+0]*xw0 + P[x*4+1]*xw1 + P[x*4+2]*xw2;
        if (q == 0) {
            float* xla = out + OFF_XLA + ((size_t)n_idx*BPTS + b)*3;
            #pragma unroll
            for (int x = 0; x < 3; ++x) { xla[x] = xl[x]; feat[r][x] = xl[x]; }
        }
        // 12 jobs (6 octaves x sin/cos), 3 per replica q
        #pragma unroll
        for (int t = 0; t < 3; ++t) {
            const int jj  = q*3 + t;
            const int oct = jj >> 1;
            const int fn  = jj & 1;
            const float s = (float)(1 << oct);
            #pragma unroll
            for (int x = 0; x < 3; ++x) {
                float a = xl[x] * s;
                feat[r][3 + 6*oct + 3*fn + x] = fn ? cosf(a) : sinf(a);
            }
        }
    }
    __syncthreads();

    const int tc = tid & 31;   // col group
    const int tr = tid >> 5;   // row group: rows tr*8 .. tr*8+7
    float acc[8][8];

    // ---- layer 0: feat(39) -> h0 ----
    gemm_layer<39, FROW>(w0, b0, feat, acc, tc, tr);
    #pragma unroll
    for (int i = 0; i < 8; ++i) {       // relu -> h (feat distinct, no pre-barrier)
        float4 v0 = make_float4(fmaxf(acc[i][0],0.f), fmaxf(acc[i][1],0.f),
                                fmaxf(acc[i][2],0.f), fmaxf(acc[i][3],0.f));
        float4 v1 = make_float4(fmaxf(acc[i][4],0.f), fmaxf(acc[i][5],0.f),
                                fmaxf(acc[i][6],0.f), fmaxf(acc[i][7],0.f));
        *(float4*)&h[tr*8+i][tc*4]       = v0;
        *(float4*)&h[tr*8+i][128 + tc*4] = v1;
    }
    __syncthreads();

    // ---- layer 1 (in-place: read all of h, barrier, overwrite) ----
    gemm_layer<HD, HD>(w1, b1, h, acc, tc, tr);
    __syncthreads();
    #pragma unroll
    for (int i = 0; i < 8; ++i) {
        float4 v0 = make_float4(fmaxf(acc[i][0],0.f), fmaxf(acc[i][1],0.f),
                                fmaxf(acc[i][2],0.f), fmaxf(acc[i][3],0.f));
        float4 v1 = make_float4(fmaxf(acc[i][4],0.f), fmaxf(acc[i][5],0.f),
                                fmaxf(acc[i][6],0.f), fmaxf(acc[i][7],0.f));
        *(float4*)&h[tr*8+i][tc*4]       = v0;
        *(float4*)&h[tr*8+i][128 + tc*4] = v1;
    }
    __syncthreads();

    // ---- layer 2 ----
    gemm_layer<HD, HD>(w2, b2, h, acc, tc, tr);

    // ---- layer 3 from registers: pred[row] = sum_c relu(h2[row][c]) * w3[c] ----
    {
        float4 wA = *(const float4*)(w3 + tc*4);
        float4 wB = *(const float4*)(w3 + 128 + tc*4);
        float v[8];
        #pragma unroll
        for (int i = 0; i < 8; ++i) {
            float s;
            s = fmaxf(acc[i][0],0.f) * wA.x;
            s = fmaf(fmaxf(acc[i][1],0.f), wA.y, s);
            s = fmaf(fmaxf(acc[i][2],0.f), wA.z, s);
            s = fmaf(fmaxf(acc[i][3],0.f), wA.w, s);
            s = fmaf(fmaxf(acc[i][4],0.f), wB.x, s);
            s = fmaf(fmaxf(acc[i][5],0.f), wB.y, s);
            s = fmaf(fmaxf(acc[i][6],0.f), wB.z, s);
            s = fmaf(fmaxf(acc[i][7],0.f), wB.w, s);
            v[i] = s;
        }
        #pragma unroll
        for (int m = 16; m >= 1; m >>= 1) {
            #pragma unroll
            for (int i = 0; i < 8; ++i) v[i] += __shfl_xor(v[i], m);
        }
        if (tc == 0) {
            #pragma unroll
            for (int i = 0; i < 8; ++i) predp[tr*8+i] = v[i];
        }
    }
    __syncthreads();
    if (tid < TM) {
        float p = predp[tid] + b3[0];
        out[OFF_PRED + (size_t)(bbase + tid)*NPOSE + n_idx] = p;
    }
}

__global__ __launch_bounds__(256)
void select_kernel(const float* __restrict__ x_world,
                   const float* __restrict__ inv_poses,
                   const float* __restrict__ vector,
                   float* __restrict__ out)
{
    const int b = blockIdx.x * 256 + threadIdx.x;
    if (b >= BPTS) return;

    const float* pr = out + OFF_PRED + (size_t)b * NPOSE;
    float best = pr[0];
    int idx = 0;
    #pragma unroll
    for (int n = 1; n < NPOSE; ++n) {           // first-occurrence min == jnp.argmin
        float v = pr[n];
        if (v < best) { best = v; idx = n; }
    }

    float* me = out + OFF_MINENC + (size_t)b * NPOSE;
    #pragma unroll
    for (int n = 0; n < NPOSE; ++n) me[n] = (n == idx) ? 1.f : 0.f;

    const float* P = inv_poses + idx * 16;
    float* pq = out + OFF_POSEQ + (size_t)b * 16;
    #pragma unroll
    for (int m = 0; m < 16; ++m) pq[m] = P[m];

    const float xw0 = x_world[b*3+0], xw1 = x_world[b*3+1], xw2 = x_world[b*3+2];
    float* xl = out + OFF_XLOCAL + (size_t)b * 3;
    #pragma unroll
    for (int x = 0; x < 3; ++x)
        xl[x] = P[x*4+3] + P[x*4+0]*xw0 + P[x*4+1]*xw1 + P[x*4+2]*xw2;

    out[OFF_CLASS + b] = (float)idx;

    const float* vq = vector + idx * KV;
    float* ov = out + OFF_VECQ + (size_t)b * KV;
    #pragma unroll
    for (int m = 0; m < KV; ++m) ov[m] = vq[m];
}

extern "C" void kernel_launch(void* const* d_in, const int* in_sizes, int n_in,
                              void* d_out, int out_size, void* d_ws, size_t ws_size,
                              hipStream_t stream)
{
    const float* x_world   = (const float*)d_in[0];
    const float* inv_poses = (const float*)d_in[1];
    const float* vector    = (const float*)d_in[2];
    const float* w0 = (const float*)d_in[3];
    const float* b0 = (const float*)d_in[4];
    const float* w1 = (const float*)d_in[5];
    const float* b1 = (const float*)d_in[6];
    const float* w2 = (const float*)d_in[7];
    const float* b2 = (const float*)d_in[8];
    const float* w3 = (const float*)d_in[9];
    const float* b3 = (const float*)d_in[10];
    float* out = (float*)d_out;

    mlp_kernel<<<dim3(NPOSE * BPTS / TM), dim3(256), 0, stream>>>(
        x_world, inv_poses, w0, b0, w1, b1, w2, b2, w3, b3, out);
    select_kernel<<<dim3(BPTS / 256), dim3(256), 0, stream>>>(
        x_world, inv_poses, vector, out);
}